// Round 7
// baseline (2030.818 us; speedup 1.0000x reference)
//
#include <hip/hip_runtime.h>

#define NTOK (32*4096)           // 131072 tokens
#define NROWS (NTOK*5)           // 655360 flat rows
#define WF_STRIDE 6144           // 192 rows x 32
#define BF_STRIDE 192

// ---------- setup: build per-a fused weight block [192][32] ----------
// rows 0-47  : Wq (in_proj q-rows folded with agg_W, scaled 1/sqrt(24))
// rows 48-95 : Wk
// rows 96-143: WvA = outw[:,0:24] @ Wv[0:24]   (+outb folded into bias)
// rows 144-191: WvB = outw[:,24:48] @ Wv[24:48]
__global__ __launch_bounds__(256) void setup_fused(
    const float* __restrict__ aggW,  // (5,48,32)
    const float* __restrict__ aggB,  // (5,48)
    const float* __restrict__ ipw,   // (144,48)
    const float* __restrict__ ipb,   // (144)
    const float* __restrict__ outw,  // (48,48)
    const float* __restrict__ outb,  // (48)
    float* __restrict__ Wf,          // (5,192,32)
    float* __restrict__ bf)          // (5,192)
{
    const int a = (int)blockIdx.x;   // 0..4
    const int t = (int)threadIdx.x;
    __shared__ float wv[1536];       // Wv[48][32] for this a
    __shared__ float bv[48];

    for (int idx = t; idx < 1536; idx += 256) {
        int f = idx >> 5, d = idx & 31;
        float acc = 0.f;
        for (int e = 0; e < 48; ++e)
            acc += ipw[(96+f)*48 + e] * aggW[(a*48 + e)*32 + d];
        wv[idx] = acc;
    }
    if (t < 48) {
        float acc = ipb[96 + t];
        for (int e = 0; e < 48; ++e)
            acc += ipw[(96+t)*48 + e] * aggB[a*48 + e];
        bv[t] = acc;
    }
    __syncthreads();

    const float qs = 0.20412414523193154f;   // 1/sqrt(24)
    for (int idx = t; idx < 3072; idx += 256) {          // q,k rows
        int r = idx >> 5, d = idx & 31;
        float acc = 0.f;
        for (int e = 0; e < 48; ++e)
            acc += ipw[r*48 + e] * aggW[(a*48 + e)*32 + d];
        if (r < 48) acc *= qs;
        Wf[a*WF_STRIDE + idx] = acc;
    }
    for (int idx = t; idx < 3072; idx += 256) {          // vA,vB rows
        int rr = idx >> 5, d = idx & 31;
        int j  = (rr < 48) ? rr : rr - 48;
        int fb = (rr < 48) ? 0 : 24;
        float acc = 0.f;
        for (int ff = 0; ff < 24; ++ff)
            acc += outw[j*48 + fb + ff] * wv[(fb + ff)*32 + d];
        Wf[a*WF_STRIDE + 3072 + idx] = acc;
    }
    if (t < 96) {                                        // q,k biases
        float acc = ipb[t];
        for (int e = 0; e < 48; ++e)
            acc += ipw[t*48 + e] * aggB[a*48 + e];
        if (t < 48) acc *= qs;
        bf[a*BF_STRIDE + t] = acc;
    } else if (t < 192) {                                // vA,vB biases
        int rr = t - 96;
        int j  = (rr < 48) ? rr : rr - 48;
        int fb = (rr < 48) ? 0 : 24;
        float acc = (rr < 48) ? outb[j] : 0.f;           // outb once (sum p = 1)
        for (int ff = 0; ff < 24; ++ff)
            acc += outw[j*48 + fb + ff] * bv[fb + ff];
        bf[a*BF_STRIDE + t] = acc;
    }
}

__device__ __forceinline__ void load_xchunk(const float* __restrict__ p, float xr[32])
{
    const float4* xv = reinterpret_cast<const float4*>(p);
#pragma unroll
    for (int i = 0; i < 8; ++i) {
        float4 t = xv[i];
        xr[4*i+0] = t.x; xr[4*i+1] = t.y; xr[4*i+2] = t.z; xr[4*i+3] = t.w;
    }
}

// 32-term dot vs LDS weight row; 4 accumulators (dep chain ~32cy)
__device__ __forceinline__ float row32(const float* __restrict__ wrow, const float xr[32], float bias)
{
    const float4* wp = reinterpret_cast<const float4*>(wrow);
    float a0 = bias, a1 = 0.f, a2 = 0.f, a3 = 0.f;
#pragma unroll
    for (int i = 0; i < 2; ++i) {
        float4 w4 = wp[i];
        a0 = fmaf(w4.x, xr[4*i+0], a0); a0 = fmaf(w4.y, xr[4*i+1], a0);
        a0 = fmaf(w4.z, xr[4*i+2], a0); a0 = fmaf(w4.w, xr[4*i+3], a0);
    }
#pragma unroll
    for (int i = 2; i < 4; ++i) {
        float4 w4 = wp[i];
        a1 = fmaf(w4.x, xr[4*i+0], a1); a1 = fmaf(w4.y, xr[4*i+1], a1);
        a1 = fmaf(w4.z, xr[4*i+2], a1); a1 = fmaf(w4.w, xr[4*i+3], a1);
    }
#pragma unroll
    for (int i = 4; i < 6; ++i) {
        float4 w4 = wp[i];
        a2 = fmaf(w4.x, xr[4*i+0], a2); a2 = fmaf(w4.y, xr[4*i+1], a2);
        a2 = fmaf(w4.z, xr[4*i+2], a2); a2 = fmaf(w4.w, xr[4*i+3], a2);
    }
#pragma unroll
    for (int i = 6; i < 8; ++i) {
        float4 w4 = wp[i];
        a3 = fmaf(w4.x, xr[4*i+0], a3); a3 = fmaf(w4.y, xr[4*i+1], a3);
        a3 = fmaf(w4.z, xr[4*i+2], a3); a3 = fmaf(w4.w, xr[4*i+3], a3);
    }
    return (a0 + a1) + (a2 + a3);
}

// ---------- shared attention body ----------
// One thread = one (token m, row aq). Block blk covers flat rows [blk*240, +240).
// NSETS=1: all rows in one weight page (guaranteed by caller). NSETS=2: stage both.
template<int NSETS>
__device__ __forceinline__ void attn_body(
    int blk, const float* __restrict__ x,
    const float* __restrict__ Wf, const float* __restrict__ bf,
    float* __restrict__ out, float* sW, float* sB)
{
    const int t = (int)threadIdx.x;
    const unsigned g0 = (unsigned)blk * 240u;
    const unsigned u0 = g0 >> 12;
    const unsigned a0 = u0 - 5u*((u0*52429u) >> 18);     // u0 % 5

    // ---- stage weight set(s) ----
    {
        const float4* s0p = reinterpret_cast<const float4*>(Wf + a0*WF_STRIDE);
        float4* d0 = reinterpret_cast<float4*>(sW);
#pragma unroll
        for (int i = 0; i < 6; ++i) d0[t + 256*i] = s0p[t + 256*i];
        if (t < BF_STRIDE) sB[t] = bf[a0*BF_STRIDE + t];
        if (NSETS == 2) {
            const unsigned a1 = (a0 == 4u) ? 0u : a0 + 1u;
            const float4* s1p = reinterpret_cast<const float4*>(Wf + a1*WF_STRIDE);
            float4* d1 = reinterpret_cast<float4*>(sW + WF_STRIDE);
#pragma unroll
            for (int i = 0; i < 6; ++i) d1[t + 256*i] = s1p[t + 256*i];
            if (t < BF_STRIDE) sB[BF_STRIDE + t] = bf[a1*BF_STRIDE + t];
        }
    }
    __syncthreads();

    const int lane = t & 63;
    if (lane >= 60) return;
    const int wv_ = t >> 6;
    const unsigned m_base = ((unsigned)blk*4u + (unsigned)wv_)*12u;
    const unsigned tok5 = (unsigned)lane / 5u;
    const unsigned aq   = (unsigned)lane - tok5*5u;
    const unsigned m = m_base + tok5;
    if (m >= NTOK) return;

    const unsigned g  = 5u*m_base + (unsigned)lane;      // == 5m + aq
    const unsigned u  = g >> 12;
    const unsigned bb = (u*52429u) >> 18;                // u/5
    const unsigned a  = u - 5u*bb;                       // u%5 -> weight page
    const float* xp = x + ((((bb<<12) | (g & 4095u)) << 8) + (a<<5));

    const float* myW;
    const float* myB;
    if (NSETS == 1) { myW = sW; myB = sB; }
    else {
        const int sel = (a == a0) ? 0 : 1;
        myW = sW + sel*WF_STRIDE;
        myB = sB + sel*BF_STRIDE;
    }

    float xr[32]; load_xchunk(xp, xr);

    const int base4 = (lane - (int)aq)*4;
    int ad[4];
#pragma unroll
    for (int r = 0; r < 4; ++r) {
        int sl = (int)aq + r + 1; if (sl >= 5) sl -= 5;
        ad[r] = base4 + sl*4;
    }

    // ---------- QK: stream q_e,k_e; accumulate scores ----------
    float s0[5] = {0,0,0,0,0}, s1[5] = {0,0,0,0,0};
#pragma unroll 1
    for (int e = 0; e < 24; ++e) {
        float qe = row32(myW + e*32, xr, myB[e]);
        float ke = row32(myW + (48+e)*32, xr, myB[48+e]);
        s0[0] = fmaf(qe, ke, s0[0]);
#pragma unroll
        for (int r = 0; r < 4; ++r) {
            float kr = __int_as_float(__builtin_amdgcn_ds_bpermute(ad[r], __float_as_int(ke)));
            s0[r+1] = fmaf(qe, kr, s0[r+1]);
        }
    }
#pragma unroll 1
    for (int e = 24; e < 48; ++e) {
        float qe = row32(myW + e*32, xr, myB[e]);
        float ke = row32(myW + (48+e)*32, xr, myB[48+e]);
        s1[0] = fmaf(qe, ke, s1[0]);
#pragma unroll
        for (int r = 0; r < 4; ++r) {
            float kr = __int_as_float(__builtin_amdgcn_ds_bpermute(ad[r], __float_as_int(ke)));
            s1[r+1] = fmaf(qe, kr, s1[r+1]);
        }
    }

    // ---------- softmax ----------
    float p0[5], p1[5];
    {
        float mx = fmaxf(fmaxf(fmaxf(s0[0], s0[1]), fmaxf(s0[2], s0[3])), s0[4]);
        float e0 = __expf(s0[0]-mx), e1 = __expf(s0[1]-mx), e2 = __expf(s0[2]-mx),
              e3 = __expf(s0[3]-mx), e4 = __expf(s0[4]-mx);
        float inv = 1.0f/(e0+e1+e2+e3+e4);
        p0[0]=e0*inv; p0[1]=e1*inv; p0[2]=e2*inv; p0[3]=e3*inv; p0[4]=e4*inv;
    }
    {
        float mx = fmaxf(fmaxf(fmaxf(s1[0], s1[1]), fmaxf(s1[2], s1[3])), s1[4]);
        float e0 = __expf(s1[0]-mx), e1 = __expf(s1[1]-mx), e2 = __expf(s1[2]-mx),
              e3 = __expf(s1[3]-mx), e4 = __expf(s1[4]-mx);
        float inv = 1.0f/(e0+e1+e2+e3+e4);
        p1[0]=e0*inv; p1[1]=e1*inv; p1[2]=e2*inv; p1[3]=e3*inv; p1[4]=e4*inv;
    }

    // ---------- PV with pre-folded out-proj: out[e] = sum_r p0[r]*vA_r[e] + p1[r]*vB_r[e] ----------
    float* __restrict__ dst = out + (size_t)m*512u + aq*48u;
#pragma unroll 1
    for (int eg = 0; eg < 6; ++eg) {
        float oj[8];
#pragma unroll
        for (int e2 = 0; e2 < 8; ++e2) {
            const int e = eg*8 + e2;
            float vA = row32(myW + (96+e)*32,  xr, myB[96+e]);
            float vB = row32(myW + (144+e)*32, xr, myB[144+e]);
            float oe = p0[0]*vA + p1[0]*vB;
#pragma unroll
            for (int r = 0; r < 4; ++r) {
                float vAr = __int_as_float(__builtin_amdgcn_ds_bpermute(ad[r], __float_as_int(vA)));
                float vBr = __int_as_float(__builtin_amdgcn_ds_bpermute(ad[r], __float_as_int(vB)));
                oe = fmaf(p0[r+1], vAr, oe);
                oe = fmaf(p1[r+1], vBr, oe);
            }
            oj[e2] = oe;
        }
        float4* d4 = reinterpret_cast<float4*>(dst + eg*8);
        d4[0] = make_float4(oj[0], oj[1], oj[2], oj[3]);
        d4[1] = make_float4(oj[4], oj[5], oj[6], oj[7]);
    }
}

// main: single-set blocks only (straddle blocks early-exit)
__global__ __launch_bounds__(256, 5) void attn_main(
    const float* __restrict__ x, const float* __restrict__ Wf,
    const float* __restrict__ bf, float* __restrict__ out)
{
    __shared__ float sW[WF_STRIDE];
    __shared__ float sB[BF_STRIDE];
    const int blk = (int)blockIdx.x;
    const unsigned g0 = (unsigned)blk*240u;
    unsigned gend = g0 + 239u; if (gend > NROWS-1u) gend = NROWS-1u;
    if ((g0 >> 12) != (gend >> 12)) return;              // handled by attn_straddle
    attn_body<1>(blk, x, Wf, bf, out, sW, sB);
}

// cleanup: the ~159 page-straddling blocks, dual-set LDS
__global__ __launch_bounds__(256) void attn_straddle(
    const float* __restrict__ x, const float* __restrict__ Wf,
    const float* __restrict__ bf, float* __restrict__ out)
{
    __shared__ float sW[2*WF_STRIDE];
    __shared__ float sB[2*BF_STRIDE];
    const int bi = (int)blockIdx.x + 1;                  // boundary 1..159
    const int blk = (bi << 12) / 240;                    // block containing row bi*4096
    const unsigned g0 = (unsigned)blk*240u;
    unsigned gend = g0 + 239u; if (gend > NROWS-1u) gend = NROWS-1u;
    if ((g0 >> 12) == (gend >> 12)) return;              // boundary-aligned: main handled it
    attn_body<2>(blk, x, Wf, bf, out, sW, sB);
}

// ---------- extra path: col-quarters (68 cols), w-quarter in LDS staged once ----------
__global__ __launch_bounds__(256, 4) void extra_gemm(
    const float* __restrict__ x,     // (32,4096,256)
    const float* __restrict__ exw,   // (272,96)
    const float* __restrict__ exb,   // (272,)
    float* __restrict__ out)         // cols [240,512)
{
    __shared__ float sw2[17*96*4];   // 26112 B

    const int t = (int)threadIdx.x;
    const unsigned tb = blockIdx.x >> 2;
    const int quarter = (int)(blockIdx.x & 3u);
    const int colbase = quarter*68;

    // stage transposed w-quarter: sw2[c4][k][j] = exw[colbase+c4*4+j][k]
#pragma unroll 1
    for (int q = t; q < 1632; q += 256) {
        int row = q / 24;                 // local col 0..67
        int kp  = (q - row*24)*4;         // k 0..92
        float4 v = *reinterpret_cast<const float4*>(
            exw + (size_t)(colbase + row)*96u + (unsigned)kp);
        int c4 = row >> 2, jp = row & 3;
        float* dp = sw2 + (c4*96 + kp)*4 + jp;
        dp[0] = v.x; dp[4] = v.y; dp[8] = v.z; dp[12] = v.w;
    }

    const unsigned m = tb*256u + (unsigned)t;
    float xr[96];
    {
        const float4* xp = reinterpret_cast<const float4*>(x + (size_t)m*256u + 160u);
#pragma unroll
        for (int i = 0; i < 24; ++i) {
            float4 v = xp[i];
            xr[4*i+0]=v.x; xr[4*i+1]=v.y; xr[4*i+2]=v.z; xr[4*i+3]=v.w;
        }
    }
    __syncthreads();

    float* __restrict__ dst = out + (size_t)m*512u + 240u + (unsigned)colbase;
    const float* bp = exb + colbase;
#pragma unroll 1
    for (int c4 = 0; c4 < 17; ++c4) {
        const float4* wp = reinterpret_cast<const float4*>(sw2 + c4*384);
        float4 acc = make_float4(bp[c4*4+0], bp[c4*4+1], bp[c4*4+2], bp[c4*4+3]);
#pragma unroll
        for (int k = 0; k < 96; ++k) {
            float4 w4 = wp[k];
            acc.x = fmaf(w4.x, xr[k], acc.x);
            acc.y = fmaf(w4.y, xr[k], acc.y);
            acc.z = fmaf(w4.z, xr[k], acc.z);
            acc.w = fmaf(w4.w, xr[k], acc.w);
        }
        reinterpret_cast<float4*>(dst)[c4] = acc;
    }
}

// ---------------- launch ----------------
extern "C" void kernel_launch(void* const* d_in, const int* in_sizes, int n_in,
                              void* d_out, int out_size, void* d_ws, size_t ws_size,
                              hipStream_t stream)
{
    const float* x    = (const float*)d_in[0];
    const float* aggW = (const float*)d_in[1];
    const float* aggB = (const float*)d_in[2];
    const float* ipw  = (const float*)d_in[3];
    const float* ipb  = (const float*)d_in[4];
    const float* outw = (const float*)d_in[5];
    const float* outb = (const float*)d_in[6];
    const float* exw  = (const float*)d_in[7];
    const float* exb  = (const float*)d_in[8];
    float* out = (float*)d_out;

    float* Wf = (float*)d_ws;                 // 5*6144 floats
    float* bf = Wf + 5*WF_STRIDE;             // 5*192 floats (~127 KB total)

    setup_fused<<<dim3(5), dim3(256), 0, stream>>>(aggW, aggB, ipw, ipb, outw, outb, Wf, bf);
    attn_main<<<dim3((NROWS + 239)/240), dim3(256), 0, stream>>>(x, Wf, bf, out);
    attn_straddle<<<dim3(159), dim3(256), 0, stream>>>(x, Wf, bf, out);
    extra_gemm<<<dim3((NTOK/256)*4), dim3(256), 0, stream>>>(x, exw, exb, out);
}